// Round 7
// baseline (1288.423 us; speedup 1.0000x reference)
//
#include <hip/hip_runtime.h>

// Problem: S=512, B=256, I=64, H=512, O=25.
// y depends only on batch row 255 (out[:, -1, :]) and the recurrence is
// per-row independent -> compute only row 255.
//
// R6 post-mortem: phase-bit protocol requires per-location monotonicity at a
// single coherence point; the L2/memory dual-copy broke it and the init
// pattern (sign=1) collided with phase 1 -> stale zeros. R7 fixes this with
// EXACT STEP TAGS: mailbox entry = (tag=s+1, value) dwordx2; accept only
// tag==s+1. Stale/init values can only delay, never corrupt. Agent-scope
// (L3) mailbox polled every 8th spin guarantees progress even if the
// same-XCD L2 path never delivers (cross-XCD placement).
//
//   rnn_pre : xi[t][h] = x[t,255,:].W_ih[h,:] + b_ih[h] + b_hh[h];
//             block (0,0) re-inits election state + both mailboxes (tag=0).
//   rnn_seq : 512 sequential steps h = relu(xi_t + W_hh h_prev) on 8 worker
//             blocks elected onto ONE XCD (HW_REG_XCC_ID ticket election over
//             256 candidates), 512 threads, 64 rows/block, w[64]/thread.
//             Publish: plain dwordx2 store -> winner-XCD L2 (+ agent store to
//             L3 box). Poll: sc0 dwordx2 loads from L2 (~200cyc period) with
//             agent-scope escape hatch every 8 spins. Double-buffered by s&1;
//             data-dependency bounds skew <2 steps; exact tag disambiguates.
//   rnn_post: y[t] = h_t . W2^T + b2   (512x25)

#define S_ 512
#define B_ 256
#define I_ 64
#define H_ 512
#define O_ 25
#define W_ 8     // worker blocks (same XCD)
#define RW_ 64   // rows per worker
#define TW_ 512  // threads per rnn_seq block
#define NB_ 256  // candidate blocks (pigeonhole: some XCD gets >= W_)

typedef unsigned long long u64;

__global__ __launch_bounds__(256) void rnn_pre(
    const float* __restrict__ x, const float* __restrict__ W_ih,
    const float* __restrict__ b_ih, const float* __restrict__ b_hh,
    float* __restrict__ xi, u64* __restrict__ l2box,
    u64* __restrict__ l3box, unsigned* __restrict__ elect) {
  const int t = blockIdx.x;
  const int tid = threadIdx.x;
  const int o = blockIdx.y * 256 + tid;
  if (t == 0 && blockIdx.y == 0) {
    // tag=0 never matches wanted tags (s+1 in [1,512]); re-done every launch.
    for (int j = tid; j < 2 * H_; j += 256) {
      l2box[j] = 0ull;
      l3box[j] = 0ull;
    }
    if (tid < 9) elect[tid] = 0u;  // [0..7]=per-XCD tickets, [8]=winner
  }
  __shared__ float xr[I_];
  if (tid < I_) xr[tid] = x[(t * B_ + (B_ - 1)) * I_ + tid];
  __syncthreads();
  float acc = b_ih[o] + b_hh[o];
  const float4* wp = (const float4*)(W_ih + o * I_);
#pragma unroll
  for (int j = 0; j < I_ / 4; ++j) {
    float4 w4 = wp[j];
    acc += w4.x * xr[4 * j] + w4.y * xr[4 * j + 1] + w4.z * xr[4 * j + 2] +
           w4.w * xr[4 * j + 3];
  }
  xi[t * H_ + o] = acc;
}

__global__ __launch_bounds__(TW_) void rnn_seq(
    const float* __restrict__ W_hh, const float* __restrict__ xi,
    float* __restrict__ hseq, u64* __restrict__ l2box,
    u64* __restrict__ l3box, unsigned* __restrict__ elect) {
  const int tid = threadIdx.x;

  // ---- same-XCD election (thread 0, broadcast via LDS) ----
  __shared__ int role_s;
  if (tid == 0) {
    unsigned xcc;
    asm volatile("s_getreg_b32 %0, hwreg(HW_REG_XCC_ID)" : "=s"(xcc));
    xcc &= 7u;
    unsigned tk = atomicAdd(&elect[xcc], 1u);  // device-scope
    int role = -1;
    if (tk < W_) {
      if (tk == W_ - 1) atomicCAS(&elect[8], 0u, xcc + 1u);
      unsigned win;
      do {  // some XCD is guaranteed to reach W_ tickets
        win = __hip_atomic_load(&elect[8], __ATOMIC_RELAXED,
                                __HIP_MEMORY_SCOPE_AGENT);
      } while (win == 0u);
      if (win == xcc + 1u) role = (int)tk;
    }
    role_s = role;
  }
  __syncthreads();
  const int b = role_s;
  if (b < 0) return;  // not a worker

  // ---- worker: 64 rows, 8 lanes/row, w[64] register-resident ----
  const int seg = tid & 7;
  const int row_l = tid >> 3;
  const int row = b * RW_ + row_l;
  const int own_lo = b * RW_;
  const bool fin = (seg == 0);

  __shared__ float h_l[2][H_];  // double-buffered h

  // strided cols: chunk j at element 4*(seg+8j); per-wave LDS reads are
  // 8 distinct addresses over 32 banks + broadcast = conflict-free
  float w[64];
  {
    const float4* wrow = (const float4*)(W_hh + row * H_);
#pragma unroll
    for (int j = 0; j < 16; ++j) {
      float4 v = wrow[seg + 8 * j];
      w[4 * j] = v.x; w[4 * j + 1] = v.y; w[4 * j + 2] = v.z; w[4 * j + 3] = v.w;
    }
  }
  for (int n = tid; n < H_; n += TW_) h_l[0][n] = 0.0f;  // h_{-1} = 0
  float xiv = fin ? xi[row] : 0.0f;
  __syncthreads();

  // one remote poll entry per thread (448 pollers, 64 idle)
  const int e = (tid < H_ - RW_) ? (tid + ((tid >= own_lo) ? RW_ : 0)) : -1;

  for (int s = 0; s < S_; ++s) {
    const float* hr = h_l[s & 1];
    float* hw = h_l[(s + 1) & 1];
    const unsigned want = (unsigned)(s + 1);   // exact step tag
    const int boff = (s & 1) * H_;

    // partial dot over 64 strided cols, 4 accumulator chains
    float a0 = 0.f, a1 = 0.f, a2 = 0.f, a3 = 0.f;
    const float4* hp = (const float4*)hr;
#pragma unroll
    for (int j = 0; j < 16; ++j) {
      float4 hv = hp[seg + 8 * j];
      a0 = fmaf(w[4 * j + 0], hv.x, a0);
      a1 = fmaf(w[4 * j + 1], hv.y, a1);
      a2 = fmaf(w[4 * j + 2], hv.z, a2);
      a3 = fmaf(w[4 * j + 3], hv.w, a3);
    }
    float acc = (a0 + a1) + (a2 + a3);
    acc += __shfl_xor(acc, 1, 64);   // fold the 8 seg lanes
    acc += __shfl_xor(acc, 2, 64);
    acc += __shfl_xor(acc, 4, 64);

    if (fin) {
      float h = fmaxf(acc + xiv, 0.0f);
      hw[row] = h;                    // own row: LDS-direct
      hseq[s * H_ + row] = h;         // for rnn_post
      u64 pk = ((u64)want << 32) | (u64)__float_as_uint(h);
      // L2 publish: plain store lands in this XCD's L2 (vL1 is read-only)
      asm volatile("global_store_dwordx2 %0, %1, off"
                   :: "v"(l2box + boff + row), "v"(pk) : "memory");
      // L3 publish (agent scope): guarantees eventual delivery everywhere
      __hip_atomic_store(&l3box[boff + row], pk, __ATOMIC_RELAXED,
                         __HIP_MEMORY_SCOPE_AGENT);
    }

    if (s == S_ - 1) break;                  // nothing to consume after last
    if (fin) xiv = xi[(s + 1) * H_ + row];   // prefetch under poll

    if (e >= 0) {
      const u64* ap = l2box + boff + e;
      u64 q;
      int it = 0;
      while (true) {
        // sc0: bypass vL1, read shared L2 copy
        asm volatile("global_load_dwordx2 %0, %1, off sc0\n\ts_waitcnt vmcnt(0)"
                     : "=v"(q) : "v"(ap) : "memory");
        if ((unsigned)(q >> 32) == want) break;
        if ((++it & 7) == 0) {
          // agent-scope escape hatch: l3box copy is monotone at the device
          // coherence point -> eventual exact-tag delivery, never stale-accept
          q = __hip_atomic_load(&l3box[boff + e], __ATOMIC_RELAXED,
                                __HIP_MEMORY_SCOPE_AGENT);
          if ((unsigned)(q >> 32) == want) break;
        }
      }
      hw[e] = __uint_as_float((unsigned)q);
    }
    __syncthreads();
  }
}

__global__ __launch_bounds__(256) void rnn_post(
    const float* __restrict__ hseq, const float* __restrict__ W2,
    const float* __restrict__ b2, float* __restrict__ y) {
  const int t = blockIdx.x;
  const int tid = threadIdx.x;
  __shared__ float hl[H_];
  __shared__ float part[256];
  for (int n = tid; n < H_; n += 256) hl[n] = hseq[t * H_ + n];
  __syncthreads();
  const int o = tid >> 3;
  const int seg = tid & 7;
  float acc = 0.0f;
  if (o < O_) {
    const float4* wp = (const float4*)(W2 + o * H_ + seg * 64);
    const float4* hp = (const float4*)(hl + seg * 64);
#pragma unroll
    for (int j = 0; j < 16; ++j) {
      float4 w4 = wp[j];
      float4 h4 = hp[j];
      acc += w4.x * h4.x + w4.y * h4.y + w4.z * h4.z + w4.w * h4.w;
    }
  }
  part[tid] = acc;
  __syncthreads();
  if (tid < O_) {
    float sum = 0.0f;
#pragma unroll
    for (int j = 0; j < 8; ++j) sum += part[tid * 8 + j];
    y[t * O_ + tid] = sum + b2[tid];
  }
}

extern "C" void kernel_launch(void* const* d_in, const int* in_sizes, int n_in,
                              void* d_out, int out_size, void* d_ws, size_t ws_size,
                              hipStream_t stream) {
  const float* x    = (const float*)d_in[0];
  const float* W_ih = (const float*)d_in[1];
  const float* W_hh = (const float*)d_in[2];
  const float* b_ih = (const float*)d_in[3];
  const float* b_hh = (const float*)d_in[4];
  const float* W2   = (const float*)d_in[5];
  const float* b2   = (const float*)d_in[6];
  float* y = (float*)d_out;

  float* xi   = (float*)d_ws;                  // [512*512] f32
  float* hseq = xi + S_ * H_;                  // [512*512] f32
  u64* l2box  = (u64*)(hseq + S_ * H_);        // [2*512] (tag,value)
  u64* l3box  = l2box + 2 * H_;                // [2*512] (tag,value)
  unsigned* elect = (unsigned*)(l3box + 2 * H_);  // [9]

  rnn_pre<<<dim3(S_, 2), 256, 0, stream>>>(x, W_ih, b_ih, b_hh, xi,
                                           l2box, l3box, elect);
  rnn_seq<<<NB_, TW_, 0, stream>>>(W_hh, xi, hseq, l2box, l3box, elect);
  rnn_post<<<S_, 256, 0, stream>>>(hseq, W2, b2, y);
}